// Round 1
// baseline (1052.119 us; speedup 1.0000x reference)
//
#include <hip/hip_runtime.h>
#include <stdint.h>

#define DIMD 4096   // feature width (and K)
#define DIMB 4096   // batch
#define NLAYER 4

typedef unsigned short u16;
typedef __attribute__((ext_vector_type(4))) float f32x4;
typedef __attribute__((ext_vector_type(8))) __bf16 bf16x8;

__device__ __forceinline__ u16 f2bf(float f) {
    union { float f; uint32_t u; } v; v.f = f;
    return (u16)((v.u + 0x7fffu + ((v.u >> 16) & 1u)) >> 16);  // RNE
}

// ---------------- fp32 -> bf16 elementwise (x input) ----------------
__global__ void k_cvt(const float* __restrict__ in, u16* __restrict__ out) {
    int i = (blockIdx.x * 256 + threadIdx.x) * 4;
    float4 v = *reinterpret_cast<const float4*>(in + i);
    ushort4 r;
    r.x = f2bf(v.x); r.y = f2bf(v.y); r.z = f2bf(v.z); r.w = f2bf(v.w);
    *reinterpret_cast<ushort4*>(out + i) = r;
}

// ---------------- W[k][n] fp32 -> Wt[n][k] bf16 (transpose+convert) ----------------
__global__ void k_trans(const float* __restrict__ W, u16* __restrict__ Wt) {
    __shared__ float tile[32][33];
    int tx = threadIdx.x & 31, ty = threadIdx.x >> 5;  // 32 x 8
    int n0 = blockIdx.x * 32, k0 = blockIdx.y * 32;
    #pragma unroll
    for (int r = 0; r < 4; ++r)
        tile[ty + r * 8][tx] = W[(size_t)(k0 + ty + r * 8) * DIMD + n0 + tx];
    __syncthreads();
    #pragma unroll
    for (int r = 0; r < 4; ++r) {
        int nn = ty + r * 8;
        Wt[(size_t)(n0 + nn) * DIMD + k0 + tx] = f2bf(tile[tx][nn]);
    }
}

// ---------------- bf16 MFMA GEMM: C = A[4096xK] * Wt[NxK]^T + bias ----------------
// 128x128 tile, BK=32, 4 waves (2x2), each wave 64x64 (4x4 frags of 16x16x32).
// LDS staged via global_load_lds width=16 with XOR chunk swizzle (applied on the
// pre-swizzled GLOBAL source + on the ds_read address; LDS itself stays linear).
// Epilogue: bias add, store fp32 C, per-column sum/sumsq atomics for BN stats.
#define GLD(g, l) __builtin_amdgcn_global_load_lds( \
    (__attribute__((address_space(1))) void*)(g),   \
    (__attribute__((address_space(3))) void*)(l), 16, 0, 0)

__global__ __launch_bounds__(256) void k_gemm(
        const u16* __restrict__ A, const u16* __restrict__ Bt,
        const float* __restrict__ bias, float* __restrict__ C,
        float* __restrict__ csum, float* __restrict__ csum2) {
    __shared__ __attribute__((aligned(16))) u16 As[128 * 32];
    __shared__ __attribute__((aligned(16))) u16 Bs[128 * 32];
    const int tid = threadIdx.x;
    const int lane = tid & 63, wv = tid >> 6;
    const int bm = blockIdx.y, bn = blockIdx.x;
    const int wrow = (wv >> 1) * 64, wcol = (wv & 1) * 64;

    // Staging: tile = 128 rows x 4 chunks (16B = 8 bf16 each) = 512 chunks.
    // LDS chunk q holds global k-chunk (q&3) ^ ((row>>1)&3)  [row = q>>2].
    const int q0 = tid, q1 = tid + 256;
    const int r0 = q0 >> 2, c0 = (q0 & 3) ^ ((r0 >> 1) & 3);
    const int r1 = q1 >> 2, c1 = (q1 & 3) ^ ((r1 >> 1) & 3);
    const u16* gA0 = A + (size_t)(bm * 128 + r0) * DIMD + c0 * 8;
    const u16* gA1 = A + (size_t)(bm * 128 + r1) * DIMD + c1 * 8;
    const u16* gB0 = Bt + (size_t)(bn * 128 + r0) * DIMD + c0 * 8;
    const u16* gB1 = Bt + (size_t)(bn * 128 + r1) * DIMD + c1 * 8;
    // wave-uniform LDS bases (hardware writes base + lane*16)
    u16* lA0 = As + wv * 512;
    u16* lA1 = As + 2048 + wv * 512;
    u16* lB0 = Bs + wv * 512;
    u16* lB1 = Bs + 2048 + wv * 512;

    const int lr = lane & 15, lk = lane >> 4;
    int aoff[4], boff[4];
    #pragma unroll
    for (int m = 0; m < 4; ++m) {
        int ra = wrow + m * 16 + lr;
        aoff[m] = ra * 32 + ((lk ^ ((ra >> 1) & 3)) << 3);
        int rb = wcol + m * 16 + lr;
        boff[m] = rb * 32 + ((lk ^ ((rb >> 1) & 3)) << 3);
    }

    f32x4 acc[4][4] = {};

    GLD(gA0, lA0); GLD(gA1, lA1); GLD(gB0, lB0); GLD(gB1, lB1);

    for (int kt = 0; kt < DIMD / 32; ++kt) {
        __syncthreads();                       // staging of kt complete
        bf16x8 af[4], bg[4];
        #pragma unroll
        for (int m = 0; m < 4; ++m) af[m] = *reinterpret_cast<const bf16x8*>(As + aoff[m]);
        #pragma unroll
        for (int n = 0; n < 4; ++n) bg[n] = *reinterpret_cast<const bf16x8*>(Bs + boff[n]);
        __syncthreads();                       // all waves done reading LDS
        if (kt + 1 < DIMD / 32) {              // async-stage next tile under MFMA
            int ko = (kt + 1) * 32;
            GLD(gA0 + ko, lA0); GLD(gA1 + ko, lA1);
            GLD(gB0 + ko, lB0); GLD(gB1 + ko, lB1);
        }
        #pragma unroll
        for (int m = 0; m < 4; ++m)
            #pragma unroll
            for (int n = 0; n < 4; ++n)
                acc[m][n] = __builtin_amdgcn_mfma_f32_16x16x32_bf16(af[m], bg[n], acc[m][n], 0, 0, 0);
    }

    // Epilogue: C/D layout col = lane&15, row = (lane>>4)*4 + reg
    #pragma unroll
    for (int n = 0; n < 4; ++n) {
        int col = bn * 128 + wcol + n * 16 + lr;
        float bv = bias[col];
        float s1 = 0.f, s2 = 0.f;
        #pragma unroll
        for (int m = 0; m < 4; ++m) {
            int rbase = bm * 128 + wrow + m * 16 + lk * 4;
            #pragma unroll
            for (int r = 0; r < 4; ++r) {
                float v = acc[m][n][r] + bv;
                C[(size_t)(rbase + r) * DIMD + col] = v;
                s1 += v; s2 += v * v;
            }
        }
        // lanes {l, l^16, l^32, l^48} share the same column
        s1 += __shfl_xor(s1, 16); s1 += __shfl_xor(s1, 32);
        s2 += __shfl_xor(s2, 16); s2 += __shfl_xor(s2, 32);
        if (lk == 0) {
            atomicAdd(&csum[col], s1);
            atomicAdd(&csum2[col], s2);
        }
    }
}

// ---------------- BN stats -> per-column scale/shift ----------------
__global__ void k_bnfin(float* __restrict__ sum, float* __restrict__ sum2,
                        const float* __restrict__ gamma, const float* __restrict__ beta) {
    int j = blockIdx.x * 256 + threadIdx.x;
    float mu = sum[j] * (1.0f / DIMB);
    float var = sum2[j] * (1.0f / DIMB) - mu * mu;
    float rstd = rsqrtf(var + 1e-5f);
    float s = gamma[j] * rstd;
    sum[j] = s;
    sum2[j] = beta[j] - mu * s;
}

// ---------------- normalize + relu -> bf16 (layers 0..2) ----------------
__global__ void k_norm(const float* __restrict__ H, const float* __restrict__ s,
                       const float* __restrict__ t, u16* __restrict__ o) {
    int j = blockIdx.x * 256 + threadIdx.x;
    int i0 = blockIdx.y * 128;
    float sj = s[j], tj = t[j];
    for (int i = i0; i < i0 + 128; ++i) {
        float v = fmaxf(H[(size_t)i * DIMD + j] * sj + tj, 0.0f);
        o[(size_t)i * DIMD + j] = f2bf(v);
    }
}

// ---------------- layer 3: normalize + relu + exp in place, column exp-sums ----------------
__global__ void k_normexp(float* __restrict__ H, const float* __restrict__ s,
                          const float* __restrict__ t, float* __restrict__ esum) {
    int j = blockIdx.x * 256 + threadIdx.x;
    int i0 = blockIdx.y * 128;
    float sj = s[j], tj = t[j];
    float acc = 0.f;
    for (int i = i0; i < i0 + 128; ++i) {
        float v = fmaxf(H[(size_t)i * DIMD + j] * sj + tj, 0.0f);
        float e = __expf(v);          // v in [0,~8]: no overflow, max-subtract unnecessary
        H[(size_t)i * DIMD + j] = e;
        acc += e;
    }
    atomicAdd(&esum[j], acc);
}

// ---------------- softmax divide, in place ----------------
__global__ void k_div(float* __restrict__ H, const float* __restrict__ esum) {
    int i = (blockIdx.x * 256 + threadIdx.x) * 4;
    float4 v = *reinterpret_cast<const float4*>(H + i);
    const float4 e = *reinterpret_cast<const float4*>(esum + (i & (DIMD - 1)));
    v.x /= e.x; v.y /= e.y; v.z /= e.z; v.w /= e.w;
    *reinterpret_cast<float4*>(H + i) = v;
}

extern "C" void kernel_launch(void* const* d_in, const int* in_sizes, int n_in,
                              void* d_out, int out_size, void* d_ws, size_t ws_size,
                              hipStream_t stream) {
    (void)in_sizes; (void)n_in; (void)out_size; (void)ws_size;
    const float* x     = (const float*)d_in[0];
    const float* W     = (const float*)d_in[1];
    const float* b     = (const float*)d_in[2];
    const float* gamma = (const float*)d_in[3];
    const float* beta  = (const float*)d_in[4];
    float* out = (float*)d_out;                       // doubles as H scratch (fp32 4096x4096)

    char* ws = (char*)d_ws;
    u16*  Abf   = (u16*)ws;                           // 32 MiB activation bf16
    u16*  Wt    = (u16*)(ws + (size_t)32 * 1024 * 1024);  // 32 MiB transposed weights bf16
    float* stats = (float*)(ws + (size_t)64 * 1024 * 1024);
    // stats layout: per layer l: sum = stats + l*8192, sum2 = sum + 4096; esum = stats + 32768
    hipMemsetAsync(stats, 0, (4 * 8192 + 4096) * sizeof(float), stream);

    k_cvt<<<DIMB * DIMD / 1024, 256, 0, stream>>>(x, Abf);

    for (int l = 0; l < NLAYER; ++l) {
        k_trans<<<dim3(128, 128), 256, 0, stream>>>(W + (size_t)l * DIMD * DIMD, Wt);
        float* sum = stats + l * 8192;
        float* sum2 = sum + 4096;
        k_gemm<<<dim3(32, 32), 256, 0, stream>>>(Abf, Wt, b + l * DIMD, out, sum, sum2);
        k_bnfin<<<16, 256, 0, stream>>>(sum, sum2, gamma + l * DIMD, beta + l * DIMD);
        if (l < NLAYER - 1)
            k_norm<<<dim3(16, 32), 256, 0, stream>>>(out, sum, sum2, Abf);
        else
            k_normexp<<<dim3(16, 32), 256, 0, stream>>>(out, sum, sum2, stats + 32768);
    }
    k_div<<<DIMB * DIMD / 1024, 256, 0, stream>>>(out, stats + 32768);
}

// Round 2
// 789.922 us; speedup vs baseline: 1.3319x; 1.3319x over previous
//
#include <hip/hip_runtime.h>
#include <stdint.h>

#define DIMD 4096   // feature width (and K)
#define DIMB 4096   // batch
#define NLAYER 4
#define NT (DIMD / 64)   // 64 K-tiles of BK=64

typedef unsigned short u16;
typedef __attribute__((ext_vector_type(4))) float f32x4;
typedef __attribute__((ext_vector_type(8))) __bf16 bf16x8;

__device__ __forceinline__ u16 f2bf(float f) {
    union { float f; uint32_t u; } v; v.f = f;
    return (u16)((v.u + 0x7fffu + ((v.u >> 16) & 1u)) >> 16);  // RNE
}

// ---------------- fp32 -> bf16 elementwise (x input) ----------------
__global__ void k_cvt(const float* __restrict__ in, u16* __restrict__ out) {
    int i = (blockIdx.x * 256 + threadIdx.x) * 4;
    float4 v = *reinterpret_cast<const float4*>(in + i);
    ushort4 r;
    r.x = f2bf(v.x); r.y = f2bf(v.y); r.z = f2bf(v.z); r.w = f2bf(v.w);
    *reinterpret_cast<ushort4*>(out + i) = r;
}

// ---------------- W[k][n] fp32 -> Wt[n][k] bf16 (transpose+convert) ----------------
__global__ void k_trans(const float* __restrict__ W, u16* __restrict__ Wt) {
    __shared__ float tile[32][33];
    int tx = threadIdx.x & 31, ty = threadIdx.x >> 5;  // 32 x 8
    int n0 = blockIdx.x * 32, k0 = blockIdx.y * 32;
    #pragma unroll
    for (int r = 0; r < 4; ++r)
        tile[ty + r * 8][tx] = W[(size_t)(k0 + ty + r * 8) * DIMD + n0 + tx];
    __syncthreads();
    #pragma unroll
    for (int r = 0; r < 4; ++r) {
        int nn = ty + r * 8;
        Wt[(size_t)(n0 + nn) * DIMD + k0 + tx] = f2bf(tile[tx][nn]);
    }
}

// ---------------- 256x256 8-phase bf16 MFMA GEMM ----------------
// BM=BN=256, BK=64, 512 threads = 8 waves (2M x 4N), per-wave 128x64 output.
// LDS: A,B tiles double-buffered = 128 KiB. XOR chunk swizzle (8 chunks of 16B
// per 128B row, chunk' = chunk ^ (row&7)) applied on the pre-swizzled GLOBAL
// source and on the ds_read address; LDS written linearly by global_load_lds.
// Per K-tile: 4 phases, each {ds_reads; 1 half-tile stage (2 GLD); barrier;
// MFMA x16 under setprio}; counted vmcnt(2) once per tile (never 0 mid-loop).
#define GLD(g, l) __builtin_amdgcn_global_load_lds( \
    (__attribute__((address_space(1))) void*)(g),   \
    (__attribute__((address_space(3))) void*)(l), 16, 0, 0)

__global__ __launch_bounds__(512, 2) void k_gemm(
        const u16* __restrict__ A, const u16* __restrict__ Bt,
        const float* __restrict__ bias, float* __restrict__ C,
        float* __restrict__ csum, float* __restrict__ csum2) {
    __shared__ __attribute__((aligned(16))) u16 As[2 * 256 * 64];   // 64 KiB
    __shared__ __attribute__((aligned(16))) u16 Bs[2 * 256 * 64];   // 64 KiB
    const int tid = threadIdx.x;
    const int lane = tid & 63, wv = tid >> 6;
    const int wm = wv >> 2, wn = wv & 3;          // 2 x 4 wave grid
    const int bm = blockIdx.y, bn = blockIdx.x;
    const int lr = lane & 15, lk = lane >> 4;

    // ---- staging geometry: per issue, 512 threads x 16B cover 64 rows x 64 cols
    const int r0 = tid >> 3;                       // 0..63
    const int cswz = (tid & 7) ^ (r0 & 7);         // inverse-swizzled 16B chunk
    const u16* gA = A  + (size_t)(bm * 256 + r0) * DIMD + cswz * 8;
    const u16* gB = Bt + (size_t)(bn * 256 + r0) * DIMD + cswz * 8;

    // unit = one matrix half (128 rows x 64 cols = 16 KiB = 2 GLD issues)
#define STAGE_A(h, t, buf) do { \
    const u16* _s = gA + (size_t)(h) * 128 * DIMD + (size_t)(t) * 64; \
    u16* _d = As + (buf) * 16384 + (h) * 8192 + wv * 512; \
    GLD(_s, _d); GLD(_s + (size_t)64 * DIMD, _d + 4096); \
} while (0)
#define STAGE_B(h, t, buf) do { \
    const u16* _s = gB + (size_t)(h) * 128 * DIMD + (size_t)(t) * 64; \
    u16* _d = Bs + (buf) * 16384 + (h) * 8192 + wv * 512; \
    GLD(_s, _d); GLD(_s + (size_t)64 * DIMD, _d + 4096); \
} while (0)

    // ---- ds_read fragment offsets (u16 units), swizzled
    // A row = wm*128 + mh*64 + mf*16 + lr ; chunk = ks*4 + lk
    // mh adds 64 rows = +4096 u16 (row&7 unchanged -> same swizzle)
    int aoff[4][2], boff[2][2];
    #pragma unroll
    for (int mf = 0; mf < 4; ++mf)
        #pragma unroll
        for (int ks = 0; ks < 2; ++ks) {
            int row = wm * 128 + mf * 16 + lr;
            aoff[mf][ks] = row * 64 + ((ks * 4 + lk) ^ (row & 7)) * 8;
        }
    #pragma unroll
    for (int nf = 0; nf < 2; ++nf)
        #pragma unroll
        for (int ks = 0; ks < 2; ++ks) {
            int row = wn * 64 + nf * 16 + lr;
            boff[nf][ks] = row * 64 + ((ks * 4 + lk) ^ (row & 7)) * 8;
        }

    f32x4 acc[8][4] = {};          // [mh*4+mf][nh*2+nf]
    bf16x8 a[4][2], b0[2][2], b1[2][2];

    // ---- prologue: tile 0 complete + A-lo(1); counted wait
    STAGE_A(0, 0, 0); STAGE_A(1, 0, 0); STAGE_B(0, 0, 0); STAGE_B(1, 0, 0);
    STAGE_A(0, 1, 1);
    asm volatile("s_waitcnt vmcnt(2)" ::: "memory");
    __builtin_amdgcn_s_barrier();

    for (int t = 0; t < NT; ++t) {
        const int cur = t & 1, nxt = cur ^ 1;
        const u16* Ab = As + cur * 16384;
        const u16* Bb = Bs + cur * 16384;

        // ===== P1: read A[mh=0] + B[nh=0]; stage A-hi(t+1); MFMA q(0,0)
        #pragma unroll
        for (int mf = 0; mf < 4; ++mf)
            #pragma unroll
            for (int ks = 0; ks < 2; ++ks)
                a[mf][ks] = *reinterpret_cast<const bf16x8*>(Ab + aoff[mf][ks]);
        #pragma unroll
        for (int nf = 0; nf < 2; ++nf)
            #pragma unroll
            for (int ks = 0; ks < 2; ++ks)
                b0[nf][ks] = *reinterpret_cast<const bf16x8*>(Bb + boff[nf][ks]);
        if (t + 1 < NT) STAGE_A(1, t + 1, nxt);
        __builtin_amdgcn_s_barrier();
        asm volatile("s_waitcnt lgkmcnt(0)" ::: "memory");
        __builtin_amdgcn_s_setprio(1);
        #pragma unroll
        for (int mf = 0; mf < 4; ++mf)
            #pragma unroll
            for (int nf = 0; nf < 2; ++nf)
                #pragma unroll
                for (int ks = 0; ks < 2; ++ks)
                    acc[mf][nf] = __builtin_amdgcn_mfma_f32_16x16x32_bf16(
                        a[mf][ks], b0[nf][ks], acc[mf][nf], 0, 0, 0);
        __builtin_amdgcn_s_setprio(0);
        __builtin_amdgcn_s_barrier();

        // ===== P2: read B[nh=1]; stage B-lo(t+1); MFMA q(0,1)
        #pragma unroll
        for (int nf = 0; nf < 2; ++nf)
            #pragma unroll
            for (int ks = 0; ks < 2; ++ks)
                b1[nf][ks] = *reinterpret_cast<const bf16x8*>(Bb + 2048 + boff[nf][ks]);
        if (t + 1 < NT) STAGE_B(0, t + 1, nxt);
        __builtin_amdgcn_s_barrier();
        asm volatile("s_waitcnt lgkmcnt(0)" ::: "memory");
        __builtin_amdgcn_s_setprio(1);
        #pragma unroll
        for (int mf = 0; mf < 4; ++mf)
            #pragma unroll
            for (int nf = 0; nf < 2; ++nf)
                #pragma unroll
                for (int ks = 0; ks < 2; ++ks)
                    acc[mf][2 + nf] = __builtin_amdgcn_mfma_f32_16x16x32_bf16(
                        a[mf][ks], b1[nf][ks], acc[mf][2 + nf], 0, 0, 0);
        __builtin_amdgcn_s_setprio(0);
        __builtin_amdgcn_s_barrier();

        // ===== P3: read A[mh=1]; stage B-hi(t+1); MFMA q(1,1)
        #pragma unroll
        for (int mf = 0; mf < 4; ++mf)
            #pragma unroll
            for (int ks = 0; ks < 2; ++ks)
                a[mf][ks] = *reinterpret_cast<const bf16x8*>(Ab + 4096 + aoff[mf][ks]);
        if (t + 1 < NT) STAGE_B(1, t + 1, nxt);
        __builtin_amdgcn_s_barrier();
        asm volatile("s_waitcnt lgkmcnt(0)" ::: "memory");
        __builtin_amdgcn_s_setprio(1);
        #pragma unroll
        for (int mf = 0; mf < 4; ++mf)
            #pragma unroll
            for (int nf = 0; nf < 2; ++nf)
                #pragma unroll
                for (int ks = 0; ks < 2; ++ks)
                    acc[4 + mf][2 + nf] = __builtin_amdgcn_mfma_f32_16x16x32_bf16(
                        a[mf][ks], b1[nf][ks], acc[4 + mf][2 + nf], 0, 0, 0);
        __builtin_amdgcn_s_setprio(0);
        __builtin_amdgcn_s_barrier();

        // ===== P4: stage A-lo(t+2) (same buffer — safe: A reads ended at P3);
        //           MFMA q(1,0) reusing b0; counted vmcnt; tile-boundary barrier
        if (t + 2 < NT) STAGE_A(0, t + 2, cur);
        __builtin_amdgcn_s_setprio(1);
        #pragma unroll
        for (int mf = 0; mf < 4; ++mf)
            #pragma unroll
            for (int nf = 0; nf < 2; ++nf)
                #pragma unroll
                for (int ks = 0; ks < 2; ++ks)
                    acc[4 + mf][nf] = __builtin_amdgcn_mfma_f32_16x16x32_bf16(
                        a[mf][ks], b0[nf][ks], acc[4 + mf][nf], 0, 0, 0);
        __builtin_amdgcn_s_setprio(0);
        if (t + 2 < NT) asm volatile("s_waitcnt vmcnt(2)" ::: "memory");
        else            asm volatile("s_waitcnt vmcnt(0)" ::: "memory");
        __builtin_amdgcn_s_barrier();
    }

    // ---- epilogue: bias, fp32 C, BN stats (col = lane&15 group; row = lk*4+r)
    #pragma unroll
    for (int nh = 0; nh < 2; ++nh)
        #pragma unroll
        for (int nf = 0; nf < 2; ++nf) {
            int n = nh * 2 + nf;
            int col = bn * 256 + wn * 64 + nh * 32 + nf * 16 + lr;
            float bv = bias[col];
            float s1 = 0.f, s2 = 0.f;
            #pragma unroll
            for (int m = 0; m < 8; ++m) {
                int rbase = bm * 256 + wm * 128 + (m >> 2) * 64 + (m & 3) * 16 + lk * 4;
                #pragma unroll
                for (int r = 0; r < 4; ++r) {
                    float v = acc[m][n][r] + bv;
                    C[(size_t)(rbase + r) * DIMD + col] = v;
                    s1 += v; s2 += v * v;
                }
            }
            s1 += __shfl_xor(s1, 16); s1 += __shfl_xor(s1, 32);
            s2 += __shfl_xor(s2, 16); s2 += __shfl_xor(s2, 32);
            if (lk == 0) {
                atomicAdd(&csum[col], s1);
                atomicAdd(&csum2[col], s2);
            }
        }
#undef STAGE_A
#undef STAGE_B
}

// ---------------- BN stats -> per-column scale/shift ----------------
__global__ void k_bnfin(float* __restrict__ sum, float* __restrict__ sum2,
                        const float* __restrict__ gamma, const float* __restrict__ beta) {
    int j = blockIdx.x * 256 + threadIdx.x;
    float mu = sum[j] * (1.0f / DIMB);
    float var = sum2[j] * (1.0f / DIMB) - mu * mu;
    float rstd = rsqrtf(var + 1e-5f);
    float s = gamma[j] * rstd;
    sum[j] = s;
    sum2[j] = beta[j] - mu * s;
}

// ---------------- normalize + relu -> bf16 (layers 0..2) ----------------
__global__ void k_norm(const float* __restrict__ H, const float* __restrict__ s,
                       const float* __restrict__ t, u16* __restrict__ o) {
    int j = blockIdx.x * 256 + threadIdx.x;
    int i0 = blockIdx.y * 128;
    float sj = s[j], tj = t[j];
    for (int i = i0; i < i0 + 128; ++i) {
        float v = fmaxf(H[(size_t)i * DIMD + j] * sj + tj, 0.0f);
        o[(size_t)i * DIMD + j] = f2bf(v);
    }
}

// ---------------- layer 3: normalize + relu + exp in place, column exp-sums ----------------
__global__ void k_normexp(float* __restrict__ H, const float* __restrict__ s,
                          const float* __restrict__ t, float* __restrict__ esum) {
    int j = blockIdx.x * 256 + threadIdx.x;
    int i0 = blockIdx.y * 128;
    float sj = s[j], tj = t[j];
    float acc = 0.f;
    for (int i = i0; i < i0 + 128; ++i) {
        float v = fmaxf(H[(size_t)i * DIMD + j] * sj + tj, 0.0f);
        float e = __expf(v);          // v in [0,~8]: no overflow, max-subtract unnecessary
        H[(size_t)i * DIMD + j] = e;
        acc += e;
    }
    atomicAdd(&esum[j], acc);
}

// ---------------- softmax divide, in place ----------------
__global__ void k_div(float* __restrict__ H, const float* __restrict__ esum) {
    int i = (blockIdx.x * 256 + threadIdx.x) * 4;
    float4 v = *reinterpret_cast<const float4*>(H + i);
    const float4 e = *reinterpret_cast<const float4*>(esum + (i & (DIMD - 1)));
    v.x /= e.x; v.y /= e.y; v.z /= e.z; v.w /= e.w;
    *reinterpret_cast<float4*>(H + i) = v;
}

extern "C" void kernel_launch(void* const* d_in, const int* in_sizes, int n_in,
                              void* d_out, int out_size, void* d_ws, size_t ws_size,
                              hipStream_t stream) {
    (void)in_sizes; (void)n_in; (void)out_size; (void)ws_size;
    const float* x     = (const float*)d_in[0];
    const float* W     = (const float*)d_in[1];
    const float* b     = (const float*)d_in[2];
    const float* gamma = (const float*)d_in[3];
    const float* beta  = (const float*)d_in[4];
    float* out = (float*)d_out;                       // doubles as H scratch (fp32 4096x4096)

    char* ws = (char*)d_ws;
    u16*  Abf   = (u16*)ws;                               // 32 MiB activation bf16
    u16*  Wt    = (u16*)(ws + (size_t)32 * 1024 * 1024);  // 32 MiB transposed weights bf16
    float* stats = (float*)(ws + (size_t)64 * 1024 * 1024);
    // stats layout: per layer l: sum = stats + l*8192, sum2 = sum + 4096; esum = stats + 32768
    hipMemsetAsync(stats, 0, (4 * 8192 + 4096) * sizeof(float), stream);

    k_cvt<<<DIMB * DIMD / 1024, 256, 0, stream>>>(x, Abf);

    for (int l = 0; l < NLAYER; ++l) {
        k_trans<<<dim3(128, 128), 256, 0, stream>>>(W + (size_t)l * DIMD * DIMD, Wt);
        float* sum = stats + l * 8192;
        float* sum2 = sum + 4096;
        k_gemm<<<dim3(16, 16), 512, 0, stream>>>(Abf, Wt, b + l * DIMD, out, sum, sum2);
        k_bnfin<<<16, 256, 0, stream>>>(sum, sum2, gamma + l * DIMD, beta + l * DIMD);
        if (l < NLAYER - 1)
            k_norm<<<dim3(16, 32), 256, 0, stream>>>(out, sum, sum2, Abf);
        else
            k_normexp<<<dim3(16, 32), 256, 0, stream>>>(out, sum, sum2, stats + 32768);
    }
    k_div<<<DIMB * DIMD / 1024, 256, 0, stream>>>(out, stats + 32768);
}

// Round 3
// 733.730 us; speedup vs baseline: 1.4339x; 1.0766x over previous
//
#include <hip/hip_runtime.h>
#include <stdint.h>

#define DIMD 4096   // feature width (and K)
#define DIMB 4096   // batch
#define NLAYER 4
#define NT (DIMD / 64)   // 64 K-tiles of BK=64

typedef unsigned short u16;
typedef __attribute__((ext_vector_type(4))) float f32x4;
typedef __attribute__((ext_vector_type(8))) __bf16 bf16x8;

__device__ __forceinline__ u16 f2bf(float f) {
    union { float f; uint32_t u; } v; v.f = f;
    return (u16)((v.u + 0x7fffu + ((v.u >> 16) & 1u)) >> 16);  // RNE
}

// ---------------- fp32 -> bf16 elementwise (x input) ----------------
__global__ void k_cvt(const float* __restrict__ in, u16* __restrict__ out) {
    int i = (blockIdx.x * 256 + threadIdx.x) * 4;
    float4 v = *reinterpret_cast<const float4*>(in + i);
    ushort4 r;
    r.x = f2bf(v.x); r.y = f2bf(v.y); r.z = f2bf(v.z); r.w = f2bf(v.w);
    *reinterpret_cast<ushort4*>(out + i) = r;
}

// ---------------- W[k][n] fp32 -> Wt[n][k] bf16 (transpose+convert) ----------------
// 64x64 tile: reads 256B contiguous per k-row, writes 128B contiguous per n-row.
__global__ void k_trans(const float* __restrict__ W, u16* __restrict__ Wt) {
    __shared__ float tile[64][65];
    const int t = threadIdx.x;
    const int n0 = blockIdx.x * 64, k0 = blockIdx.y * 64;
    const int kr = t >> 4, c4 = (t & 15) * 4;
    #pragma unroll
    for (int r = 0; r < 4; ++r) {
        float4 v = *reinterpret_cast<const float4*>(W + (size_t)(k0 + kr + r * 16) * DIMD + n0 + c4);
        tile[kr + r * 16][c4 + 0] = v.x;
        tile[kr + r * 16][c4 + 1] = v.y;
        tile[kr + r * 16][c4 + 2] = v.z;
        tile[kr + r * 16][c4 + 3] = v.w;
    }
    __syncthreads();
    const int nr = t >> 4, k4 = (t & 15) * 4;
    #pragma unroll
    for (int r = 0; r < 4; ++r) {
        int n = nr + r * 16;
        ushort4 o;
        o.x = f2bf(tile[k4 + 0][n]);
        o.y = f2bf(tile[k4 + 1][n]);
        o.z = f2bf(tile[k4 + 2][n]);
        o.w = f2bf(tile[k4 + 3][n]);
        *reinterpret_cast<ushort4*>(Wt + (size_t)(n0 + n) * DIMD + k0 + k4) = o;
    }
}

// ---------------- 256x256 8-phase bf16 MFMA GEMM ----------------
// BM=BN=256, BK=64, 512 threads = 8 waves (2M x 4N), per-wave 128x64 output.
// LDS: A,B tiles double-buffered = 128 KiB. XOR chunk swizzle (8 chunks of 16B
// per 128B row, chunk' = chunk ^ (row&7)) on the pre-swizzled GLOBAL source +
// the ds_read address; LDS written linearly by global_load_lds.
// Counted-vmcnt pipeline (T4): stage tile t+2's B units at P3(t), A units at
// P4(t); one s_waitcnt vmcnt(8) per tile (4 half-tiles in flight, each load
// drains 4-5 phases after issue). Region safety: B regions of buf(t) are
// read-complete after P2(t), A regions after P3(t) — issues sit after those
// barriers. All units of tile t+1 drain at P4(t)'s vmcnt before the tile-end
// barrier, so P1(t+1)'s ds_reads are safe.
#define GLD(g, l) __builtin_amdgcn_global_load_lds( \
    (__attribute__((address_space(1))) void*)(g),   \
    (__attribute__((address_space(3))) void*)(l), 16, 0, 0)

__global__ __launch_bounds__(512, 2) void k_gemm(
        const u16* __restrict__ A, const u16* __restrict__ Bt,
        const float* __restrict__ bias, float* __restrict__ C,
        float* __restrict__ csum, float* __restrict__ csum2) {
    __shared__ __attribute__((aligned(16))) u16 As[2 * 256 * 64];   // 64 KiB
    __shared__ __attribute__((aligned(16))) u16 Bs[2 * 256 * 64];   // 64 KiB
    const int tid = threadIdx.x;
    const int lane = tid & 63, wv = tid >> 6;
    const int wm = wv >> 2, wn = wv & 3;          // 2 x 4 wave grid
    const int bm = blockIdx.y, bn = blockIdx.x;
    const int lr = lane & 15, lk = lane >> 4;

    // ---- staging geometry: per GLD issue, 512 threads x 16B cover 64 rows x 64 cols
    const int r0 = tid >> 3;                       // 0..63
    const int cswz = (tid & 7) ^ (r0 & 7);         // inverse-swizzled 16B chunk
    const u16* gA = A  + (size_t)(bm * 256 + r0) * DIMD + cswz * 8;
    const u16* gB = Bt + (size_t)(bn * 256 + r0) * DIMD + cswz * 8;

    // unit = one matrix half (128 rows x 64 cols = 16 KiB = 2 GLD issues)
#define STAGE_A(h, t, buf) do { \
    const u16* _s = gA + (size_t)(h) * 128 * DIMD + (size_t)(t) * 64; \
    u16* _d = As + (buf) * 16384 + (h) * 8192 + wv * 512; \
    GLD(_s, _d); GLD(_s + (size_t)64 * DIMD, _d + 4096); \
} while (0)
#define STAGE_B(h, t, buf) do { \
    const u16* _s = gB + (size_t)(h) * 128 * DIMD + (size_t)(t) * 64; \
    u16* _d = Bs + (buf) * 16384 + (h) * 8192 + wv * 512; \
    GLD(_s, _d); GLD(_s + (size_t)64 * DIMD, _d + 4096); \
} while (0)

    // ---- ds_read fragment offsets (u16 units), swizzled
    int aoff[4][2], boff[2][2];
    #pragma unroll
    for (int mf = 0; mf < 4; ++mf)
        #pragma unroll
        for (int ks = 0; ks < 2; ++ks) {
            int row = wm * 128 + mf * 16 + lr;
            aoff[mf][ks] = row * 64 + ((ks * 4 + lk) ^ (row & 7)) * 8;
        }
    #pragma unroll
    for (int nf = 0; nf < 2; ++nf)
        #pragma unroll
        for (int ks = 0; ks < 2; ++ks) {
            int row = wn * 64 + nf * 16 + lr;
            boff[nf][ks] = row * 64 + ((ks * 4 + lk) ^ (row & 7)) * 8;
        }

    f32x4 acc[8][4] = {};          // [mh*4+mf][nh*2+nf]
    bf16x8 a[4][2], b0[2][2], b1[2][2];

    // ---- prologue: tiles 0 and 1 fully issued; drain tile 0, keep tile 1 in flight
    STAGE_B(0, 0, 0); STAGE_B(1, 0, 0); STAGE_A(0, 0, 0); STAGE_A(1, 0, 0);
    STAGE_B(0, 1, 1); STAGE_B(1, 1, 1); STAGE_A(0, 1, 1); STAGE_A(1, 1, 1);
    asm volatile("s_waitcnt vmcnt(8)" ::: "memory");
    __builtin_amdgcn_s_barrier();

    for (int t = 0; t < NT; ++t) {
        const int cur = t & 1;
        const u16* Ab = As + cur * 16384;
        const u16* Bb = Bs + cur * 16384;
        const bool pf = (t + 2 < NT);

        // ===== P1: read A[q0] + B[first 32 cols]; MFMA q(0,0)
        #pragma unroll
        for (int mf = 0; mf < 4; ++mf)
            #pragma unroll
            for (int ks = 0; ks < 2; ++ks)
                a[mf][ks] = *reinterpret_cast<const bf16x8*>(Ab + aoff[mf][ks]);
        #pragma unroll
        for (int nf = 0; nf < 2; ++nf)
            #pragma unroll
            for (int ks = 0; ks < 2; ++ks)
                b0[nf][ks] = *reinterpret_cast<const bf16x8*>(Bb + boff[nf][ks]);
        __builtin_amdgcn_s_barrier();
        asm volatile("s_waitcnt lgkmcnt(0)" ::: "memory");
        __builtin_amdgcn_s_setprio(1);
        #pragma unroll
        for (int mf = 0; mf < 4; ++mf)
            #pragma unroll
            for (int nf = 0; nf < 2; ++nf)
                #pragma unroll
                for (int ks = 0; ks < 2; ++ks)
                    acc[mf][nf] = __builtin_amdgcn_mfma_f32_16x16x32_bf16(
                        a[mf][ks], b0[nf][ks], acc[mf][nf], 0, 0, 0);
        __builtin_amdgcn_s_setprio(0);
        __builtin_amdgcn_s_barrier();

        // ===== P2: read B[second 32 cols]; MFMA q(0,1)
        #pragma unroll
        for (int nf = 0; nf < 2; ++nf)
            #pragma unroll
            for (int ks = 0; ks < 2; ++ks)
                b1[nf][ks] = *reinterpret_cast<const bf16x8*>(Bb + 2048 + boff[nf][ks]);
        __builtin_amdgcn_s_barrier();
        asm volatile("s_waitcnt lgkmcnt(0)" ::: "memory");
        __builtin_amdgcn_s_setprio(1);
        #pragma unroll
        for (int mf = 0; mf < 4; ++mf)
            #pragma unroll
            for (int nf = 0; nf < 2; ++nf)
                #pragma unroll
                for (int ks = 0; ks < 2; ++ks)
                    acc[mf][2 + nf] = __builtin_amdgcn_mfma_f32_16x16x32_bf16(
                        a[mf][ks], b1[nf][ks], acc[mf][2 + nf], 0, 0, 0);
        __builtin_amdgcn_s_setprio(0);
        __builtin_amdgcn_s_barrier();

        // ===== P3: read A[q1]; stage B-lo/B-hi(t+2) into cur (B reads done at P2);
        //           MFMA q(1,1)
        #pragma unroll
        for (int mf = 0; mf < 4; ++mf)
            #pragma unroll
            for (int ks = 0; ks < 2; ++ks)
                a[mf][ks] = *reinterpret_cast<const bf16x8*>(Ab + 4096 + aoff[mf][ks]);
        if (pf) { STAGE_B(0, t + 2, cur); STAGE_B(1, t + 2, cur); }
        __builtin_amdgcn_s_barrier();
        asm volatile("s_waitcnt lgkmcnt(0)" ::: "memory");
        __builtin_amdgcn_s_setprio(1);
        #pragma unroll
        for (int mf = 0; mf < 4; ++mf)
            #pragma unroll
            for (int nf = 0; nf < 2; ++nf)
                #pragma unroll
                for (int ks = 0; ks < 2; ++ks)
                    acc[4 + mf][2 + nf] = __builtin_amdgcn_mfma_f32_16x16x32_bf16(
                        a[mf][ks], b1[nf][ks], acc[4 + mf][2 + nf], 0, 0, 0);
        __builtin_amdgcn_s_setprio(0);
        __builtin_amdgcn_s_barrier();

        // ===== P4: stage A-lo/A-hi(t+2) into cur (A reads done at P3);
        //           MFMA q(1,0) reusing registers; counted vmcnt; tile-end barrier
        if (pf) { STAGE_A(0, t + 2, cur); STAGE_A(1, t + 2, cur); }
        __builtin_amdgcn_s_setprio(1);
        #pragma unroll
        for (int mf = 0; mf < 4; ++mf)
            #pragma unroll
            for (int nf = 0; nf < 2; ++nf)
                #pragma unroll
                for (int ks = 0; ks < 2; ++ks)
                    acc[4 + mf][nf] = __builtin_amdgcn_mfma_f32_16x16x32_bf16(
                        a[mf][ks], b0[nf][ks], acc[4 + mf][nf], 0, 0, 0);
        __builtin_amdgcn_s_setprio(0);
        if (pf) asm volatile("s_waitcnt vmcnt(8)" ::: "memory");
        else    asm volatile("s_waitcnt vmcnt(0)" ::: "memory");
        __builtin_amdgcn_s_barrier();
    }

    // ---- epilogue: bias, fp32 C, BN stats (col = lane&15 group; row = lk*4+r)
    #pragma unroll
    for (int nh = 0; nh < 2; ++nh)
        #pragma unroll
        for (int nf = 0; nf < 2; ++nf) {
            int n = nh * 2 + nf;
            int col = bn * 256 + wn * 64 + nh * 32 + nf * 16 + lr;
            float bv = bias[col];
            float s1 = 0.f, s2 = 0.f;
            #pragma unroll
            for (int m = 0; m < 8; ++m) {
                int rbase = bm * 256 + wm * 128 + (m >> 2) * 64 + (m & 3) * 16 + lk * 4;
                #pragma unroll
                for (int r = 0; r < 4; ++r) {
                    float v = acc[m][n][r] + bv;
                    C[(size_t)(rbase + r) * DIMD + col] = v;
                    s1 += v; s2 += v * v;
                }
            }
            s1 += __shfl_xor(s1, 16); s1 += __shfl_xor(s1, 32);
            s2 += __shfl_xor(s2, 16); s2 += __shfl_xor(s2, 32);
            if (lk == 0) {
                atomicAdd(&csum[col], s1);
                atomicAdd(&csum2[col], s2);
            }
        }
#undef STAGE_A
#undef STAGE_B
}

// ---------------- BN stats -> per-column scale/shift ----------------
__global__ void k_bnfin(float* __restrict__ sum, float* __restrict__ sum2,
                        const float* __restrict__ gamma, const float* __restrict__ beta) {
    int j = blockIdx.x * 256 + threadIdx.x;
    float mu = sum[j] * (1.0f / DIMB);
    float var = sum2[j] * (1.0f / DIMB) - mu * mu;
    float rstd = rsqrtf(var + 1e-5f);
    float s = gamma[j] * rstd;
    sum[j] = s;
    sum2[j] = beta[j] - mu * s;
}

// ---------------- normalize + relu -> bf16 (layers 0..2) ----------------
__global__ void k_norm(const float* __restrict__ H, const float* __restrict__ s,
                       const float* __restrict__ t, u16* __restrict__ o) {
    int j = blockIdx.x * 256 + threadIdx.x;
    int i0 = blockIdx.y * 128;
    float sj = s[j], tj = t[j];
    for (int i = i0; i < i0 + 128; ++i) {
        float v = fmaxf(H[(size_t)i * DIMD + j] * sj + tj, 0.0f);
        o[(size_t)i * DIMD + j] = f2bf(v);
    }
}

// ---------------- layer 3: normalize + relu + exp in place, column exp-sums ----------------
__global__ void k_normexp(float* __restrict__ H, const float* __restrict__ s,
                          const float* __restrict__ t, float* __restrict__ esum) {
    int j = blockIdx.x * 256 + threadIdx.x;
    int i0 = blockIdx.y * 128;
    float sj = s[j], tj = t[j];
    float acc = 0.f;
    for (int i = i0; i < i0 + 128; ++i) {
        float v = fmaxf(H[(size_t)i * DIMD + j] * sj + tj, 0.0f);
        float e = __expf(v);          // v in [0,~8]: no overflow, max-subtract unnecessary
        H[(size_t)i * DIMD + j] = e;
        acc += e;
    }
    atomicAdd(&esum[j], acc);
}

// ---------------- softmax divide, in place ----------------
__global__ void k_div(float* __restrict__ H, const float* __restrict__ esum) {
    int i = (blockIdx.x * 256 + threadIdx.x) * 4;
    float4 v = *reinterpret_cast<const float4*>(H + i);
    const float4 e = *reinterpret_cast<const float4*>(esum + (i & (DIMD - 1)));
    v.x /= e.x; v.y /= e.y; v.z /= e.z; v.w /= e.w;
    *reinterpret_cast<float4*>(H + i) = v;
}

extern "C" void kernel_launch(void* const* d_in, const int* in_sizes, int n_in,
                              void* d_out, int out_size, void* d_ws, size_t ws_size,
                              hipStream_t stream) {
    (void)in_sizes; (void)n_in; (void)out_size; (void)ws_size;
    const float* x     = (const float*)d_in[0];
    const float* W     = (const float*)d_in[1];
    const float* b     = (const float*)d_in[2];
    const float* gamma = (const float*)d_in[3];
    const float* beta  = (const float*)d_in[4];
    float* out = (float*)d_out;                       // doubles as H scratch (fp32 4096x4096)

    char* ws = (char*)d_ws;
    u16*  Abf   = (u16*)ws;                               // 32 MiB activation bf16
    u16*  Wt    = (u16*)(ws + (size_t)32 * 1024 * 1024);  // 32 MiB transposed weights bf16
    float* stats = (float*)(ws + (size_t)64 * 1024 * 1024);
    // stats layout: per layer l: sum = stats + l*8192, sum2 = sum + 4096; esum = stats + 32768
    hipMemsetAsync(stats, 0, (4 * 8192 + 4096) * sizeof(float), stream);

    k_cvt<<<DIMB * DIMD / 1024, 256, 0, stream>>>(x, Abf);

    for (int l = 0; l < NLAYER; ++l) {
        k_trans<<<dim3(64, 64), 256, 0, stream>>>(W + (size_t)l * DIMD * DIMD, Wt);
        float* sum = stats + l * 8192;
        float* sum2 = sum + 4096;
        k_gemm<<<dim3(16, 16), 512, 0, stream>>>(Abf, Wt, b + l * DIMD, out, sum, sum2);
        k_bnfin<<<16, 256, 0, stream>>>(sum, sum2, gamma + l * DIMD, beta + l * DIMD);
        if (l < NLAYER - 1)
            k_norm<<<dim3(16, 32), 256, 0, stream>>>(out, sum, sum2, Abf);
        else
            k_normexp<<<dim3(16, 32), 256, 0, stream>>>(out, sum, sum2, stats + 32768);
    }
    k_div<<<DIMB * DIMD / 1024, 256, 0, stream>>>(out, stats + 32768);
}